// Round 3
// baseline (129.294 us; speedup 1.0000x reference)
//
#include <hip/hip_runtime.h>
#include <math.h>

typedef unsigned short u16;
typedef u16 u16x4 __attribute__((ext_vector_type(4)));
typedef u16 u16x8 __attribute__((ext_vector_type(8)));
typedef float f32x4 __attribute__((ext_vector_type(4)));
typedef __bf16 bf16x8 __attribute__((ext_vector_type(8)));

#define KC 8
#define K2L 2304  // 256*9

__device__ __forceinline__ u16 f2bf_rne(float f) {
  unsigned u = __float_as_uint(f);
  u += 0x7FFFu + ((u >> 16) & 1u);
  return (u16)(u >> 16);
}
__device__ __forceinline__ float bf2f(u16 h) {
  return __uint_as_float(((unsigned)h) << 16);
}

// async global->LDS, 16B/lane; LDS dest is the WAVE-UNIFORM base (HW adds lane*16)
__device__ __forceinline__ void gload16(const u16* g, u16* l) {
  __builtin_amdgcn_global_load_lds(
      (const __attribute__((address_space(1))) unsigned*)g,
      (__attribute__((address_space(3))) unsigned*)l, 16, 0, 0);
}

// ---- split f32 -> (hi, lo) bf16 planes (GEMM1 inputs only) ----
__global__ void split_kernel(const float* __restrict__ X, u16* __restrict__ hi,
                             u16* __restrict__ lo, int n4) {
  int i = blockIdx.x * blockDim.x + threadIdx.x;
  if (i >= n4) return;
  f32x4 v = ((const f32x4*)X)[i];
  u16x4 h, l;
#pragma unroll
  for (int c = 0; c < 4; ++c) {
    u16 hb = f2bf_rne(v[c]);
    h[c] = hb;
    l[c] = f2bf_rne(v[c] - bf2f(hb));
  }
  ((u16x4*)hi)[i] = h;
  ((u16x4*)lo)[i] = l;
}

// ---- build combined weight Wc^T (N x 2304) bf16 ----
// Wc[o][i*9+0] = mask*sb ; Wc[o][i*9+1+k] = mask*sp*coef[i,o,k]
__global__ void prep_wc_kernel(const float* __restrict__ coef, const float* __restrict__ sb,
                               const float* __restrict__ sp, const float* __restrict__ mask,
                               u16* __restrict__ Whi, int N) {
  int idx = blockIdx.x * blockDim.x + threadIdx.x;
  if (idx >= N * K2L) return;
  int o = idx / K2L;
  int r = idx - o * K2L;
  int i = r / 9;
  int c = r - i * 9;
  int io = i * N + o;
  float m = mask[io];
  float v = (c == 0) ? m * sb[io] : m * sp[io] * coef[(size_t)io * KC + (c - 1)];
  Whi[idx] = f2bf_rne(v);
}

// ---- spline expand of one scalar -> 9 bf16 written to LDS ----
__device__ __forceinline__ void expand_one(float v, const float* gr, u16* dst) {
  float Bv[11];
#pragma unroll
  for (int j = 0; j < 11; ++j) Bv[j] = (v >= gr[j] && v < gr[j + 1]) ? 1.0f : 0.0f;
#pragma unroll
  for (int ki = 1; ki <= 3; ++ki) {
#pragma unroll
    for (int j = 0; j + ki < 11; ++j) {
      float t1 = (v - gr[j]) / (gr[j + ki] - gr[j]);
      float t2 = (gr[j + ki + 1] - v) / (gr[j + ki + 1] - gr[j + 1]);
      Bv[j] = t1 * Bv[j] + t2 * Bv[j + 1];
    }
  }
  dst[0] = f2bf_rne(v / (1.0f + expf(-v)));  // silu
#pragma unroll
  for (int k = 0; k < 8; ++k) dst[1 + k] = f2bf_rne(Bv[k]);
}

// ---- fused MFMA GEMM (+ optional bias+expand epilogue) ----
// C[M,N] = A[M,K] @ B[N,K]^T.  BM = MF*32, BN = NF*32, BK=64, 4 waves (2x2),
// each wave (MF*16)x(NF*16).  Double-buffered global_load_lds staging:
// linear LDS dest + inverse-swizzled global SOURCE + swizzled LDS READ
// (swizzle f(row)=row&7 on the 8x16B k-groups; involution both sides).
// EXPAND: out = bf16 F[M][N*9] (spline expansion); else out = f32 C[M][N].
template <int PLANES, int MF, int NF, bool EXPAND>
__global__ __launch_bounds__(256) void fused_gemm(
    const u16* __restrict__ Ahi, const u16* __restrict__ Alo,
    const u16* __restrict__ Bhi, const u16* __restrict__ Blo,
    const float* __restrict__ bias, const float* __restrict__ grid,
    void* __restrict__ outv, int M, int N, int K) {
  constexpr int P2 = (PLANES == 3) ? 2 : 1;
  constexpr int BM = MF * 32, BN = NF * 32;
  constexpr int ASZ = BM * 64;  // u16 per A tile
  constexpr int BSZ = BN * 64;
  constexpr int BUF_U16 = P2 * (ASZ + BSZ);
  constexpr int CA = (BM * 8) / 256;  // gload rounds per A tile
  constexpr int CB = (BN * 8) / 256;
  constexpr int STAGE_B = 2 * BUF_U16 * 2;
  constexpr int EXP_B = EXPAND ? BM * BN * 9 * 2 : 0;
  constexpr int SMEM = (STAGE_B > EXP_B) ? STAGE_B : EXP_B;
  __shared__ __align__(16) char smraw[SMEM];
  u16* smu = (u16*)smraw;

  const int tid = threadIdx.x;
  const int lane = tid & 63;
  const int wid = tid >> 6;

  // XCD-aware swizzle (grid size divisible by 8 for all our launches)
  const int nb = N / BN;
  const int nwg = (M / BM) * nb;
  const int bid = blockIdx.x;
  const int swz = (bid & 7) * (nwg >> 3) + (bid >> 3);
  const int tm = (swz / nb) * BM;
  const int tn = (swz % nb) * BN;

  const u16* gA[P2];
  const u16* gB[P2];
  gA[0] = Ahi + (size_t)tm * K;
  gB[0] = Bhi + (size_t)tn * K;
  if constexpr (P2 == 2) {
    gA[1] = Alo + (size_t)tm * K;
    gB[1] = Blo + (size_t)tn * K;
  }

  // pre-swizzled global source offset for chunk c: row=c>>3, slot s=c&7
  // holds logical k-group (s ^ (row&7))
  auto srcOff = [&](int c) -> size_t {
    int r = c >> 3, s = c & 7;
    return (size_t)r * K + (size_t)(((s ^ (r & 7)) & 7) << 3);
  };
  size_t aSrc[CA], bSrc[CB];
#pragma unroll
  for (int c = 0; c < CA; ++c) aSrc[c] = srcOff(tid + c * 256);
#pragma unroll
  for (int c = 0; c < CB; ++c) bSrc[c] = srcOff(tid + c * 256);

  const int wm = (wid >> 1) * (MF * 16);
  const int wn = (wid & 1) * (NF * 16);
  const int lrow = lane & 15;
  const int kgl = lane >> 4;

  // swizzled LDS read offsets (u16): row*64 + ((ks*4+kgl)^(row&7))*8
  int offA[MF][2], offB[NF][2];
#pragma unroll
  for (int m = 0; m < MF; ++m) {
    int row = wm + m * 16 + lrow;
#pragma unroll
    for (int ks = 0; ks < 2; ++ks)
      offA[m][ks] = row * 64 + ((((ks * 4 + kgl) ^ (row & 7)) & 7) << 3);
  }
#pragma unroll
  for (int n = 0; n < NF; ++n) {
    int row = wn + n * 16 + lrow;
#pragma unroll
    for (int ks = 0; ks < 2; ++ks)
      offB[n][ks] = row * 64 + ((((ks * 4 + kgl) ^ (row & 7)) & 7) << 3);
  }

  auto stage = [&](int b, int kk) {
    u16* sb = smu + b * BUF_U16;
#pragma unroll
    for (int p = 0; p < P2; ++p) {
#pragma unroll
      for (int c = 0; c < CA; ++c)
        gload16(gA[p] + aSrc[c] + kk, sb + p * ASZ + wid * 512 + c * 2048);
#pragma unroll
      for (int c = 0; c < CB; ++c)
        gload16(gB[p] + bSrc[c] + kk, sb + P2 * ASZ + p * BSZ + wid * 512 + c * 2048);
    }
  };

  f32x4 acc[MF][NF] = {};
  stage(0, 0);
  int cur = 0;
  for (int kk = 0; kk < K; kk += 64) {
    __syncthreads();  // drains vmcnt for buf[cur]; protects buf[cur^1] reuse
    if (kk + 64 < K) stage(cur ^ 1, kk + 64);

    const u16* sb = smu + cur * BUF_U16;
    bf16x8 af[P2][MF][2], bf[P2][NF][2];
#pragma unroll
    for (int p = 0; p < P2; ++p)
#pragma unroll
      for (int m = 0; m < MF; ++m)
#pragma unroll
        for (int ks = 0; ks < 2; ++ks)
          af[p][m][ks] = *(const bf16x8*)(sb + p * ASZ + offA[m][ks]);
#pragma unroll
    for (int p = 0; p < P2; ++p)
#pragma unroll
      for (int n = 0; n < NF; ++n)
#pragma unroll
        for (int ks = 0; ks < 2; ++ks)
          bf[p][n][ks] = *(const bf16x8*)(sb + P2 * ASZ + p * BSZ + offB[n][ks]);

#pragma unroll
    for (int m = 0; m < MF; ++m)
#pragma unroll
      for (int n = 0; n < NF; ++n)
#pragma unroll
        for (int ks = 0; ks < 2; ++ks) {
          acc[m][n] = __builtin_amdgcn_mfma_f32_16x16x32_bf16(af[0][m][ks], bf[0][n][ks], acc[m][n], 0, 0, 0);
          if constexpr (P2 == 2) {
            acc[m][n] = __builtin_amdgcn_mfma_f32_16x16x32_bf16(af[0][m][ks], bf[1][n][ks], acc[m][n], 0, 0, 0);
            acc[m][n] = __builtin_amdgcn_mfma_f32_16x16x32_bf16(af[1][m][ks], bf[0][n][ks], acc[m][n], 0, 0, 0);
          }
        }
    cur ^= 1;
  }

  const int rj = (lane >> 4) * 4;
  if constexpr (EXPAND) {
    __syncthreads();  // all frag reads done before overwriting sm
    u16* Fl = smu;
    float gr[12];
#pragma unroll
    for (int j = 0; j < 12; ++j) gr[j] = grid[j];
#pragma unroll
    for (int m = 0; m < MF; ++m)
#pragma unroll
      for (int n = 0; n < NF; ++n) {
        int col = wn + n * 16 + lrow;
        float bv = bias ? bias[tn + col] : 0.0f;
#pragma unroll
        for (int j = 0; j < 4; ++j) {
          int row = wm + m * 16 + rj + j;
          expand_one(acc[m][n][j] + bv, gr, Fl + (size_t)row * (BN * 9) + col * 9);
        }
      }
    __syncthreads();
    // coalesced copy-out: BM x (BN*9) bf16, 16B chunks
    u16* Fout = (u16*)outv;
    constexpr int RB = BN * 9 / 8;       // 16B chunks per row
    constexpr int CH = BM * RB;          // total chunks
    const size_t fstride = (size_t)N * 9;
    for (int ch = tid; ch < CH; ch += 256) {
      int r = ch / RB, o = ch - r * RB;
      *(u16x8*)(Fout + (size_t)(tm + r) * fstride + (size_t)tn * 9 + o * 8) =
          *(const u16x8*)(Fl + (size_t)ch * 8);
    }
  } else {
    float* Cp = (float*)outv + (size_t)(tm + wm) * N + (tn + wn);
#pragma unroll
    for (int m = 0; m < MF; ++m)
#pragma unroll
      for (int n = 0; n < NF; ++n)
#pragma unroll
        for (int j = 0; j < 4; ++j)
          Cp[(size_t)(m * 16 + rj + j) * N + (n * 16 + lrow)] = acc[m][n][j];
  }
}

extern "C" void kernel_launch(void* const* d_in, const int* in_sizes, int n_in,
                              void* d_out, int out_size, void* d_ws, size_t ws_size,
                              hipStream_t stream) {
  (void)in_sizes; (void)n_in; (void)out_size; (void)ws_size;
  const float* x     = (const float*)d_in[0];   // 4096x1024
  const float* W1    = (const float*)d_in[1];   // 256x1024
  const float* b1    = (const float*)d_in[2];   // 256
  const float* grid1 = (const float*)d_in[3];   // 256x12 (rows identical)
  const float* coef1 = (const float*)d_in[4];   // 256x256x8
  const float* sb1   = (const float*)d_in[5];
  const float* sp1   = (const float*)d_in[6];
  const float* mask1 = (const float*)d_in[7];
  const float* grid2 = (const float*)d_in[8];
  const float* coef2 = (const float*)d_in[9];   // 256x128x8
  const float* sb2   = (const float*)d_in[10];
  const float* sp2   = (const float*)d_in[11];
  const float* mask2 = (const float*)d_in[12];
  float* outp = (float*)d_out;

  char* ws = (char*)d_ws;
  size_t off = 0;
  auto alloc = [&](size_t bytes) {
    char* p = ws + off;
    off += (bytes + 255) & ~(size_t)255;
    return (void*)p;
  };
  u16* xs_hi  = (u16*)alloc((size_t)4096 * 1024 * 2);
  u16* xs_lo  = (u16*)alloc((size_t)4096 * 1024 * 2);
  u16* w1_hi  = (u16*)alloc((size_t)256 * 1024 * 2);
  u16* w1_lo  = (u16*)alloc((size_t)256 * 1024 * 2);
  u16* wc1    = (u16*)alloc((size_t)256 * K2L * 2);
  u16* wc2    = (u16*)alloc((size_t)128 * K2L * 2);
  u16* F1     = (u16*)alloc((size_t)4096 * K2L * 2);
  u16* F2     = (u16*)alloc((size_t)4096 * K2L * 2);

  // precision splits / weight prep
  split_kernel<<<4096, 256, 0, stream>>>(x, xs_hi, xs_lo, 4096 * 1024 / 4);
  split_kernel<<<256, 256, 0, stream>>>(W1, w1_hi, w1_lo, 256 * 1024 / 4);
  prep_wc_kernel<<<(256 * K2L) / 256, 256, 0, stream>>>(coef1, sb1, sp1, mask1, wc1, 256);
  prep_wc_kernel<<<(128 * K2L) / 256, 256, 0, stream>>>(coef2, sb2, sp2, mask2, wc2, 128);

  // Layer 1: F1 = expand(x @ W1^T + b1)   (bf16x3, M=4096,N=256,K=1024) -> 256 blocks
  fused_gemm<3, 2, 2, true><<<256, 256, 0, stream>>>(
      xs_hi, xs_lo, w1_hi, w1_lo, b1, grid1, F1, 4096, 256, 1024);

  // Layer 2: F2 = expand(F1 @ Wc1^T)      (bf16, M=4096,N=256,K=2304) -> 256 blocks
  fused_gemm<1, 2, 2, true><<<256, 256, 0, stream>>>(
      F1, nullptr, wc1, nullptr, nullptr, grid2, F2, 4096, 256, 2304);

  // Layer 3: out = F2 @ Wc2^T             (bf16, M=4096,N=128,K=2304, BM=32) -> 256 blocks
  fused_gemm<1, 1, 2, false><<<256, 256, 0, stream>>>(
      F2, nullptr, wc2, nullptr, nullptr, nullptr, outp, 4096, 128, 2304);
}

// Round 4
// 84.852 us; speedup vs baseline: 1.5238x; 1.5238x over previous
//
#include <hip/hip_runtime.h>
#include <math.h>

typedef unsigned short u16;
typedef u16 u16x4 __attribute__((ext_vector_type(4)));
typedef u16 u16x8 __attribute__((ext_vector_type(8)));
typedef float f32x4 __attribute__((ext_vector_type(4)));
typedef __bf16 bf16x8 __attribute__((ext_vector_type(8)));

#define KC 8
#define K2L 2304  // 256*9

__device__ __forceinline__ u16 f2bf_rne(float f) {
  unsigned u = __float_as_uint(f);
  u += 0x7FFFu + ((u >> 16) & 1u);
  return (u16)(u >> 16);
}
__device__ __forceinline__ float bf2f(u16 h) {
  return __uint_as_float(((unsigned)h) << 16);
}

// async global->LDS, 16B/lane; LDS dest is the WAVE-UNIFORM base (HW adds lane*16)
__device__ __forceinline__ void gload16(const u16* g, u16* l) {
  __builtin_amdgcn_global_load_lds(
      (const __attribute__((address_space(1))) unsigned*)g,
      (__attribute__((address_space(3))) unsigned*)l, 16, 0, 0);
}

// ---- split f32 -> (hi, lo) bf16 planes (GEMM1 inputs only) ----
__global__ void split_kernel(const float* __restrict__ X, u16* __restrict__ hi,
                             u16* __restrict__ lo, int n4) {
  int i = blockIdx.x * blockDim.x + threadIdx.x;
  if (i >= n4) return;
  f32x4 v = ((const f32x4*)X)[i];
  u16x4 h, l;
#pragma unroll
  for (int c = 0; c < 4; ++c) {
    u16 hb = f2bf_rne(v[c]);
    h[c] = hb;
    l[c] = f2bf_rne(v[c] - bf2f(hb));
  }
  ((u16x4*)hi)[i] = h;
  ((u16x4*)lo)[i] = l;
}

// ---- build combined weight Wc^T (N x 2304) bf16 ----
__global__ void prep_wc_kernel(const float* __restrict__ coef, const float* __restrict__ sb,
                               const float* __restrict__ sp, const float* __restrict__ mask,
                               u16* __restrict__ Whi, int N) {
  int idx = blockIdx.x * blockDim.x + threadIdx.x;
  if (idx >= N * K2L) return;
  int o = idx / K2L;
  int r = idx - o * K2L;
  int i = r / 9;
  int c = r - i * 9;
  int io = i * N + o;
  float m = mask[io];
  float v = (c == 0) ? m * sb[io] : m * sp[io] * coef[(size_t)io * KC + (c - 1)];
  Whi[idx] = f2bf_rne(v);
}

// ---- spline tables: grid + precomputed reciprocal denominators ----
struct Spl {
  float g[12];
  float d1[11], d2[10], d3[9];  // d_k[j] = 1/(g[j+k]-g[j])
};
__device__ __forceinline__ void spl_init(const float* __restrict__ grid, Spl& sp) {
#pragma unroll
  for (int j = 0; j < 12; ++j) sp.g[j] = grid[j];
#pragma unroll
  for (int j = 0; j < 11; ++j) sp.d1[j] = 1.0f / (sp.g[j + 1] - sp.g[j]);
#pragma unroll
  for (int j = 0; j < 10; ++j) sp.d2[j] = 1.0f / (sp.g[j + 2] - sp.g[j]);
#pragma unroll
  for (int j = 0; j < 9; ++j) sp.d3[j] = 1.0f / (sp.g[j + 3] - sp.g[j]);
}

// expand one scalar -> 9 bf16 [silu, B0..B7]; divide-free (mul by dinv)
__device__ __forceinline__ void expand_one(float v, const Spl& sp, u16* dst) {
  float Bv[11];
#pragma unroll
  for (int j = 0; j < 11; ++j) Bv[j] = (v >= sp.g[j] && v < sp.g[j + 1]) ? 1.0f : 0.0f;
#pragma unroll
  for (int j = 0; j < 10; ++j)
    Bv[j] = (v - sp.g[j]) * sp.d1[j] * Bv[j] + (sp.g[j + 2] - v) * sp.d1[j + 1] * Bv[j + 1];
#pragma unroll
  for (int j = 0; j < 9; ++j)
    Bv[j] = (v - sp.g[j]) * sp.d2[j] * Bv[j] + (sp.g[j + 3] - v) * sp.d2[j + 1] * Bv[j + 1];
#pragma unroll
  for (int j = 0; j < 8; ++j)
    Bv[j] = (v - sp.g[j]) * sp.d3[j] * Bv[j] + (sp.g[j + 4] - v) * sp.d3[j + 1] * Bv[j + 1];
  dst[0] = f2bf_rne(v / (1.0f + __expf(-v)));  // silu
#pragma unroll
  for (int k = 0; k < 8; ++k) dst[1 + k] = f2bf_rne(Bv[k]);
}

// ---- fused MFMA GEMM (+ optional bias+expand epilogue) ----
// C[M,N] = A[M,K] @ B[N,K]^T.  WMxWN waves, wave-tile (MF*16)x(NF*16),
// BM=WM*MF*16, BN=WN*NF*16, BK=64.  Double-buffered global_load_lds staging:
// linear LDS dest + inverse-swizzled global SOURCE + swizzled LDS READ.
template <int PLANES, int WM, int WN, int MF, int NF, bool EXPAND>
__global__ __launch_bounds__(WM * WN * 64) void fused_gemm(
    const u16* __restrict__ Ahi, const u16* __restrict__ Alo,
    const u16* __restrict__ Bhi, const u16* __restrict__ Blo,
    const float* __restrict__ bias, const float* __restrict__ grid,
    void* __restrict__ outv, int M, int N, int K) {
  constexpr int P2 = (PLANES == 3) ? 2 : 1;
  constexpr int THREADS = WM * WN * 64;
  constexpr int BM = WM * MF * 16, BN = WN * NF * 16;
  constexpr int ASZ = BM * 64;  // u16 per A tile
  constexpr int BSZ = BN * 64;
  constexpr int BUF_U16 = P2 * (ASZ + BSZ);
  constexpr int CA = (BM * 8) / THREADS;  // gload rounds per A tile
  constexpr int CB = (BN * 8) / THREADS;
  constexpr int STAGE_B = 2 * BUF_U16 * 2;
  constexpr int EXP_B = EXPAND ? BM * BN * 9 * 2 : 0;
  constexpr int SMEM = (STAGE_B > EXP_B) ? STAGE_B : EXP_B;
  __shared__ __align__(16) char smraw[SMEM];
  u16* smu = (u16*)smraw;

  const int tid = threadIdx.x;
  const int lane = tid & 63;
  const int wid = tid >> 6;

  // XCD-aware swizzle (grid sizes here are multiples of 8)
  const int nb = N / BN;
  const int nwg = (M / BM) * nb;
  const int bid = blockIdx.x;
  const int swz = (bid & 7) * (nwg >> 3) + (bid >> 3);
  const int tm = (swz / nb) * BM;
  const int tn = (swz % nb) * BN;

  const u16* gA[P2];
  const u16* gB[P2];
  gA[0] = Ahi + (size_t)tm * K;
  gB[0] = Bhi + (size_t)tn * K;
  if constexpr (P2 == 2) {
    gA[1] = Alo + (size_t)tm * K;
    gB[1] = Blo + (size_t)tn * K;
  }

  // chunk c -> row=c>>3, slot s=c&7; slot s holds logical k-group s^(row&7)
  auto srcOff = [&](int c) -> size_t {
    int r = c >> 3, s = c & 7;
    return (size_t)r * K + (size_t)(((s ^ (r & 7)) & 7) << 3);
  };
  size_t aSrc[CA], bSrc[CB];
#pragma unroll
  for (int c = 0; c < CA; ++c) aSrc[c] = srcOff(tid + c * THREADS);
#pragma unroll
  for (int c = 0; c < CB; ++c) bSrc[c] = srcOff(tid + c * THREADS);

  const int wm = (wid / WN) * (MF * 16);
  const int wn = (wid % WN) * (NF * 16);
  const int lrow = lane & 15;
  const int kgl = lane >> 4;

  int offA[MF][2], offB[NF][2];
#pragma unroll
  for (int m = 0; m < MF; ++m) {
    int row = wm + m * 16 + lrow;
#pragma unroll
    for (int ks = 0; ks < 2; ++ks)
      offA[m][ks] = row * 64 + ((((ks * 4 + kgl) ^ (row & 7)) & 7) << 3);
  }
#pragma unroll
  for (int n = 0; n < NF; ++n) {
    int row = wn + n * 16 + lrow;
#pragma unroll
    for (int ks = 0; ks < 2; ++ks)
      offB[n][ks] = row * 64 + ((((ks * 4 + kgl) ^ (row & 7)) & 7) << 3);
  }

  auto stage = [&](int b, int kk) {
    u16* sb = smu + b * BUF_U16;
#pragma unroll
    for (int p = 0; p < P2; ++p) {
#pragma unroll
      for (int c = 0; c < CA; ++c)
        gload16(gA[p] + aSrc[c] + kk, sb + p * ASZ + (c * THREADS + wid * 64) * 8);
#pragma unroll
      for (int c = 0; c < CB; ++c)
        gload16(gB[p] + bSrc[c] + kk, sb + P2 * ASZ + p * BSZ + (c * THREADS + wid * 64) * 8);
    }
  };

  f32x4 acc[MF][NF] = {};
  stage(0, 0);
  int cur = 0;
  for (int kk = 0; kk < K; kk += 64) {
    __syncthreads();  // buf[cur] loads landed; all reads of buf[cur^1] done
    if (kk + 64 < K) stage(cur ^ 1, kk + 64);

    const u16* sb = smu + cur * BUF_U16;
    bf16x8 af[P2][MF][2], bfr[P2][NF][2];
#pragma unroll
    for (int p = 0; p < P2; ++p)
#pragma unroll
      for (int m = 0; m < MF; ++m)
#pragma unroll
        for (int ks = 0; ks < 2; ++ks)
          af[p][m][ks] = *(const bf16x8*)(sb + p * ASZ + offA[m][ks]);
#pragma unroll
    for (int p = 0; p < P2; ++p)
#pragma unroll
      for (int n = 0; n < NF; ++n)
#pragma unroll
        for (int ks = 0; ks < 2; ++ks)
          bfr[p][n][ks] = *(const bf16x8*)(sb + P2 * ASZ + p * BSZ + offB[n][ks]);

#pragma unroll
    for (int m = 0; m < MF; ++m)
#pragma unroll
      for (int n = 0; n < NF; ++n)
#pragma unroll
        for (int ks = 0; ks < 2; ++ks) {
          acc[m][n] = __builtin_amdgcn_mfma_f32_16x16x32_bf16(af[0][m][ks], bfr[0][n][ks], acc[m][n], 0, 0, 0);
          if constexpr (P2 == 2) {
            acc[m][n] = __builtin_amdgcn_mfma_f32_16x16x32_bf16(af[0][m][ks], bfr[1][n][ks], acc[m][n], 0, 0, 0);
            acc[m][n] = __builtin_amdgcn_mfma_f32_16x16x32_bf16(af[1][m][ks], bfr[0][n][ks], acc[m][n], 0, 0, 0);
          }
        }
    cur ^= 1;
  }

  // C/D layout (m89-verified): col = lane&15, row = (lane>>4)*4 + j
  const int rj = (lane >> 4) * 4;
  if constexpr (EXPAND) {
    Spl sp;
    spl_init(grid, sp);
    __syncthreads();  // all frag reads done before overwriting sm
    u16* Fl = smu;
#pragma unroll
    for (int m = 0; m < MF; ++m)
#pragma unroll
      for (int n = 0; n < NF; ++n) {
        int col = wn + n * 16 + lrow;
        float bv = bias ? bias[tn + col] : 0.0f;
#pragma unroll
        for (int j = 0; j < 4; ++j) {
          int row = wm + m * 16 + rj + j;
          expand_one(acc[m][n][j] + bv, sp, Fl + (size_t)row * (BN * 9) + col * 9);
        }
      }
    __syncthreads();
    // coalesced copy-out: BM x (BN*9) bf16 in 16B chunks
    u16* Fout = (u16*)outv;
    constexpr int RB = BN * 9 / 8;
    constexpr int CH = BM * RB;
    const size_t fstride = (size_t)N * 9;
    for (int ch = tid; ch < CH; ch += THREADS) {
      int r = ch / RB, o = ch - r * RB;
      *(u16x8*)(Fout + (size_t)(tm + r) * fstride + (size_t)tn * 9 + o * 8) =
          *(const u16x8*)(Fl + (size_t)ch * 8);
    }
  } else {
    float* Cp = (float*)outv + (size_t)(tm + wm) * N + (tn + wn);
#pragma unroll
    for (int m = 0; m < MF; ++m)
#pragma unroll
      for (int n = 0; n < NF; ++n)
#pragma unroll
        for (int j = 0; j < 4; ++j)
          Cp[(size_t)(m * 16 + rj + j) * N + (n * 16 + lrow)] = acc[m][n][j];
  }
}

extern "C" void kernel_launch(void* const* d_in, const int* in_sizes, int n_in,
                              void* d_out, int out_size, void* d_ws, size_t ws_size,
                              hipStream_t stream) {
  (void)in_sizes; (void)n_in; (void)out_size; (void)ws_size;
  const float* x     = (const float*)d_in[0];   // 4096x1024
  const float* W1    = (const float*)d_in[1];   // 256x1024
  const float* b1    = (const float*)d_in[2];   // 256
  const float* grid1 = (const float*)d_in[3];   // 256x12 (rows identical)
  const float* coef1 = (const float*)d_in[4];   // 256x256x8
  const float* sb1   = (const float*)d_in[5];
  const float* sp1   = (const float*)d_in[6];
  const float* mask1 = (const float*)d_in[7];
  const float* grid2 = (const float*)d_in[8];
  const float* coef2 = (const float*)d_in[9];   // 256x128x8
  const float* sb2   = (const float*)d_in[10];
  const float* sp2   = (const float*)d_in[11];
  const float* mask2 = (const float*)d_in[12];
  float* outp = (float*)d_out;

  char* ws = (char*)d_ws;
  size_t off = 0;
  auto alloc = [&](size_t bytes) {
    char* p = ws + off;
    off += (bytes + 255) & ~(size_t)255;
    return (void*)p;
  };
  u16* xs_hi  = (u16*)alloc((size_t)4096 * 1024 * 2);
  u16* xs_lo  = (u16*)alloc((size_t)4096 * 1024 * 2);
  u16* w1_hi  = (u16*)alloc((size_t)256 * 1024 * 2);
  u16* w1_lo  = (u16*)alloc((size_t)256 * 1024 * 2);
  u16* wc1    = (u16*)alloc((size_t)256 * K2L * 2);
  u16* wc2    = (u16*)alloc((size_t)128 * K2L * 2);
  u16* F1     = (u16*)alloc((size_t)4096 * K2L * 2);
  u16* F2     = (u16*)alloc((size_t)4096 * K2L * 2);

  split_kernel<<<4096, 256, 0, stream>>>(x, xs_hi, xs_lo, 4096 * 1024 / 4);
  split_kernel<<<256, 256, 0, stream>>>(W1, w1_hi, w1_lo, 256 * 1024 / 4);
  prep_wc_kernel<<<(256 * K2L) / 256, 256, 0, stream>>>(coef1, sb1, sp1, mask1, wc1, 256);
  prep_wc_kernel<<<(128 * K2L) / 256, 256, 0, stream>>>(coef2, sb2, sp2, mask2, wc2, 128);

  // L1: F1 = expand(x @ W1^T + b1); bf16x3, 512 thr, BM=64 BN=64, grid 256
  fused_gemm<3, 4, 2, 1, 2, true><<<256, 512, 0, stream>>>(
      xs_hi, xs_lo, w1_hi, w1_lo, b1, grid1, F1, 4096, 256, 1024);

  // L2: F2 = expand(F1 @ Wc1^T); bf16, 512 thr, BM=64 BN=64, grid 256
  fused_gemm<1, 4, 2, 1, 2, true><<<256, 512, 0, stream>>>(
      F1, nullptr, wc1, nullptr, nullptr, grid2, F2, 4096, 256, 2304);

  // L3: out = F2 @ Wc2^T; bf16, 256 thr, BM=32 BN=32, grid 512
  fused_gemm<1, 2, 2, 1, 1, false><<<512, 256, 0, stream>>>(
      F2, nullptr, wc2, nullptr, nullptr, nullptr, outp, 4096, 128, 2304);
}

// Round 5
// 76.500 us; speedup vs baseline: 1.6901x; 1.1092x over previous
//
#include <hip/hip_runtime.h>
#include <math.h>

typedef unsigned short u16;
typedef u16 u16x4 __attribute__((ext_vector_type(4)));
typedef u16 u16x8 __attribute__((ext_vector_type(8)));
typedef float f32x4 __attribute__((ext_vector_type(4)));
typedef float f32x16 __attribute__((ext_vector_type(16)));
typedef __bf16 bf16x8 __attribute__((ext_vector_type(8)));

#define KC 8
#define K2L 2304  // 256*9

__device__ __forceinline__ u16 f2bf_rne(float f) {
  unsigned u = __float_as_uint(f);
  u += 0x7FFFu + ((u >> 16) & 1u);
  return (u16)(u >> 16);
}
__device__ __forceinline__ float bf2f(u16 h) {
  return __uint_as_float(((unsigned)h) << 16);
}

// async global->LDS, 16B/lane; LDS dest is the WAVE-UNIFORM base (HW adds lane*16)
__device__ __forceinline__ void gload16(const u16* g, u16* l) {
  __builtin_amdgcn_global_load_lds(
      (const __attribute__((address_space(1))) unsigned*)g,
      (__attribute__((address_space(3))) unsigned*)l, 16, 0, 0);
}

template <int N>
__device__ __forceinline__ void vmwait() {
  if constexpr (N == 0)       asm volatile("s_waitcnt vmcnt(0)" ::: "memory");
  else if constexpr (N == 4)  asm volatile("s_waitcnt vmcnt(4)" ::: "memory");
  else if constexpr (N == 6)  asm volatile("s_waitcnt vmcnt(6)" ::: "memory");
  else if constexpr (N == 8)  asm volatile("s_waitcnt vmcnt(8)" ::: "memory");
  else if constexpr (N == 12) asm volatile("s_waitcnt vmcnt(12)" ::: "memory");
  else if constexpr (N == 16) asm volatile("s_waitcnt vmcnt(16)" ::: "memory");
  else static_assert(N == 0, "unsupported vmcnt literal");
}

// ---- merged prep: split x, split W1, build Wc1, Wc2 ----
__device__ __forceinline__ void split4(const float* X, u16* hi, u16* lo, int i) {
  f32x4 v = ((const f32x4*)X)[i];
  u16x4 h, l;
#pragma unroll
  for (int c = 0; c < 4; ++c) {
    u16 hb = f2bf_rne(v[c]);
    h[c] = hb;
    l[c] = f2bf_rne(v[c] - bf2f(hb));
  }
  ((u16x4*)hi)[i] = h;
  ((u16x4*)lo)[i] = l;
}
__device__ __forceinline__ void wc_one(const float* coef, const float* sb, const float* sp,
                                       const float* mask, u16* W, int N, int idx) {
  int o = idx / K2L;
  int r = idx - o * K2L;
  int i = r / 9;
  int c = r - i * 9;
  int io = i * N + o;
  float m = mask[io];
  float v = (c == 0) ? m * sb[io] : m * sp[io] * coef[(size_t)io * KC + (c - 1)];
  W[idx] = f2bf_rne(v);
}

__global__ void prep_kernel(const float* __restrict__ x, const float* __restrict__ W1,
                            const float* __restrict__ coef1, const float* __restrict__ sb1,
                            const float* __restrict__ sp1, const float* __restrict__ mask1,
                            const float* __restrict__ coef2, const float* __restrict__ sb2,
                            const float* __restrict__ sp2, const float* __restrict__ mask2,
                            u16* __restrict__ xs_hi, u16* __restrict__ xs_lo,
                            u16* __restrict__ w1_hi, u16* __restrict__ w1_lo,
                            u16* __restrict__ wc1, u16* __restrict__ wc2) {
  const int b = blockIdx.x, tid = threadIdx.x;
  if (b < 4096) {                       // split x: 1048576 quads
    split4(x, xs_hi, xs_lo, b * 256 + tid);
  } else if (b < 4096 + 256) {          // split W1: 65536 quads
    split4(W1, w1_hi, w1_lo, (b - 4096) * 256 + tid);
  } else if (b < 4096 + 256 + 2304) {   // Wc1: 589824 elems
    wc_one(coef1, sb1, sp1, mask1, wc1, 256, (b - 4352) * 256 + tid);
  } else {                              // Wc2: 294912 elems
    wc_one(coef2, sb2, sp2, mask2, wc2, 128, (b - 6656) * 256 + tid);
  }
}

// ---- spline tables: grid + precomputed reciprocal denominators ----
struct Spl {
  float g[12];
  float d1[11], d2[10], d3[9];
};
__device__ __forceinline__ void spl_init(const float* __restrict__ grid, Spl& sp) {
#pragma unroll
  for (int j = 0; j < 12; ++j) sp.g[j] = grid[j];
#pragma unroll
  for (int j = 0; j < 11; ++j) sp.d1[j] = 1.0f / (sp.g[j + 1] - sp.g[j]);
#pragma unroll
  for (int j = 0; j < 10; ++j) sp.d2[j] = 1.0f / (sp.g[j + 2] - sp.g[j]);
#pragma unroll
  for (int j = 0; j < 9; ++j) sp.d3[j] = 1.0f / (sp.g[j + 3] - sp.g[j]);
}

__device__ __forceinline__ void expand_one(float v, const Spl& sp, u16* dst) {
  float Bv[11];
#pragma unroll
  for (int j = 0; j < 11; ++j) Bv[j] = (v >= sp.g[j] && v < sp.g[j + 1]) ? 1.0f : 0.0f;
#pragma unroll
  for (int j = 0; j < 10; ++j)
    Bv[j] = (v - sp.g[j]) * sp.d1[j] * Bv[j] + (sp.g[j + 2] - v) * sp.d1[j + 1] * Bv[j + 1];
#pragma unroll
  for (int j = 0; j < 9; ++j)
    Bv[j] = (v - sp.g[j]) * sp.d2[j] * Bv[j] + (sp.g[j + 3] - v) * sp.d2[j + 1] * Bv[j + 1];
#pragma unroll
  for (int j = 0; j < 8; ++j)
    Bv[j] = (v - sp.g[j]) * sp.d3[j] * Bv[j] + (sp.g[j + 4] - v) * sp.d3[j + 1] * Bv[j + 1];
  dst[0] = f2bf_rne(v / (1.0f + __expf(-v)));  // silu
#pragma unroll
  for (int k = 0; k < 8; ++k) dst[1 + k] = f2bf_rne(Bv[k]);
}

// ---- fused MFMA GEMM, 32x32x16 bf16, 3-buffer counted-vmcnt pipeline ----
// C[M,N] = A[M,K] @ B[N,K]^T.  WMxWN waves, wave-tile 32x32, BM=WM*32, BN=WN*32,
// BK=64.  Staging: linear LDS dest (global_load_lds) + inverse-swizzled global
// SOURCE + swizzled LDS READ (XOR row&7 on 16B k-slots, both sides).
// P2=2: split-precision bf16x3 (A,B hi/lo planes).  EXPAND: bias+spline epilogue.
template <int P2, int WM, int WN, bool EXPAND>
__global__ __launch_bounds__(WM * WN * 64) void fused_gemm(
    const u16* __restrict__ Ahi, const u16* __restrict__ Alo,
    const u16* __restrict__ Bhi, const u16* __restrict__ Blo,
    const float* __restrict__ bias, const float* __restrict__ grid,
    void* __restrict__ outv, int M, int N, int K) {
  constexpr int THREADS = WM * WN * 64;
  constexpr int BM = WM * 32, BN = WN * 32;
  constexpr int ASZ = BM * 64;  // u16 per A plane-tile
  constexpr int BSZ = BN * 64;
  constexpr int BUF_U16 = P2 * (ASZ + BSZ);
  constexpr int CA = (BM * 8) / THREADS;  // 16B chunks per thread (A plane)
  constexpr int CB = (BN * 8) / THREADS;
  constexpr int LPT = P2 * (CA + CB);     // gloads per thread per stage
  constexpr int STAGE_B = 3 * BUF_U16 * 2;
  constexpr int EXP_B = EXPAND ? BM * BN * 9 * 2 : 0;
  constexpr int SMEM = (STAGE_B > EXP_B) ? STAGE_B : EXP_B;
  __shared__ __align__(16) char smraw[SMEM];
  u16* smu = (u16*)smraw;

  const int tid = threadIdx.x;
  const int lane = tid & 63;
  const int wid = tid >> 6;

  // XCD-aware swizzle (grids here are multiples of 8)
  const int nb = N / BN;
  const int nwg = (M / BM) * nb;
  const int bid = blockIdx.x;
  const int swz = (bid & 7) * (nwg >> 3) + (bid >> 3);
  const int tm = (swz / nb) * BM;
  const int tn = (swz % nb) * BN;

  const u16* gA[P2];
  const u16* gB[P2];
  gA[0] = Ahi + (size_t)tm * K;
  gB[0] = Bhi + (size_t)tn * K;
  if constexpr (P2 == 2) {
    gA[1] = Alo + (size_t)tm * K;
    gB[1] = Blo + (size_t)tn * K;
  }

  // chunk c -> row=c>>3, slot s=c&7; slot s sources logical k-group s^(row&7)
  auto srcOff = [&](int c) -> size_t {
    int r = c >> 3, s = c & 7;
    return (size_t)r * K + (size_t)(((s ^ (r & 7)) & 7) << 3);
  };
  size_t aSrc[CA], bSrc[CB];
#pragma unroll
  for (int c = 0; c < CA; ++c) aSrc[c] = srcOff(tid + c * THREADS);
#pragma unroll
  for (int c = 0; c < CB; ++c) bSrc[c] = srcOff(tid + c * THREADS);

  const int wm = (wid / WN) * 32;
  const int wn = (wid % WN) * 32;
  const int lr = lane & 31;   // fragment row/col
  const int khf = lane >> 5;  // k-half selector

  // swizzled LDS read offsets (u16): row*64 + ((kgrp)^(row&7))*8, kgrp=ks*2+khf
  int offA[4], offB[4];
#pragma unroll
  for (int ks = 0; ks < 4; ++ks) {
    int rowA = wm + lr;
    int rowB = wn + lr;
    offA[ks] = rowA * 64 + ((((ks * 2 + khf) ^ (rowA & 7)) & 7) << 3);
    offB[ks] = rowB * 64 + ((((ks * 2 + khf) ^ (rowB & 7)) & 7) << 3);
  }

  auto stage = [&](int b, int kk) {
    u16* sb = smu + b * BUF_U16;
#pragma unroll
    for (int p = 0; p < P2; ++p) {
#pragma unroll
      for (int c = 0; c < CA; ++c)
        gload16(gA[p] + aSrc[c] + kk, sb + p * ASZ + (c * THREADS + wid * 64) * 8);
#pragma unroll
      for (int c = 0; c < CB; ++c)
        gload16(gB[p] + bSrc[c] + kk, sb + P2 * ASZ + p * BSZ + (c * THREADS + wid * 64) * 8);
    }
  };

  f32x16 acc0 = {}, acc1 = {};
  const int nsteps = K >> 6;
  stage(0, 0);
  if (nsteps > 1) stage(1, 64);
  for (int i = 0; i < nsteps; ++i) {
    if (i) __builtin_amdgcn_s_barrier();  // readers of buf[(i+2)%3] done (iter i-1)
    if (i + 2 < nsteps) {
      stage((i + 2) % 3, (i + 2) << 6);
      vmwait<2 * LPT>();                  // my loads for buf[i%3] landed
    } else if (i + 1 < nsteps) {
      vmwait<LPT>();
    } else {
      vmwait<0>();
    }
    __builtin_amdgcn_sched_barrier(0);
    __builtin_amdgcn_s_barrier();         // everyone's loads for buf[i%3] landed
    __builtin_amdgcn_sched_barrier(0);

    const u16* sb = smu + (i % 3) * BUF_U16;
    bf16x8 af[P2][4], bfr[P2][4];
#pragma unroll
    for (int p = 0; p < P2; ++p)
#pragma unroll
      for (int ks = 0; ks < 4; ++ks) {
        af[p][ks] = *(const bf16x8*)(sb + p * ASZ + offA[ks]);
        bfr[p][ks] = *(const bf16x8*)(sb + P2 * ASZ + p * BSZ + offB[ks]);
      }
#pragma unroll
    for (int ks = 0; ks < 4; ++ks) {
      f32x16& ac = (ks & 1) ? acc1 : acc0;  // 2 chains for MFMA ILP
      ac = __builtin_amdgcn_mfma_f32_32x32x16_bf16(af[0][ks], bfr[0][ks], ac, 0, 0, 0);
      if constexpr (P2 == 2) {
        ac = __builtin_amdgcn_mfma_f32_32x32x16_bf16(af[0][ks], bfr[1][ks], ac, 0, 0, 0);
        ac = __builtin_amdgcn_mfma_f32_32x32x16_bf16(af[1][ks], bfr[0][ks], ac, 0, 0, 0);
      }
    }
  }
  f32x16 accv = acc0 + acc1;

  // C/D layout (m74/m101): col = lane&31, row = (r&3) + 8*(r>>2) + 4*(lane>>5)
  const int col = lr;
  const int rbase = 4 * khf;
  if constexpr (EXPAND) {
    Spl sp;
    spl_init(grid, sp);
    __syncthreads();  // full drain; stage LDS reused for F tile
    u16* Fl = smu;
    const float bv = bias ? bias[tn + wn + col] : 0.0f;
#pragma unroll
    for (int r = 0; r < 16; ++r) {
      int row = wm + rbase + (r & 3) + 8 * (r >> 2);
      expand_one(accv[r] + bv, sp, Fl + (size_t)row * (BN * 9) + (wn + col) * 9);
    }
    __syncthreads();
    // coalesced copy-out: BM x (BN*9) bf16 in 16B chunks
    u16* Fout = (u16*)outv;
    constexpr int RB = BN * 9 / 8;
    constexpr int CH = BM * RB;
    const size_t fstride = (size_t)N * 9;
#pragma unroll 2
    for (int ch = tid; ch < CH; ch += THREADS) {
      int r = ch / RB, o = ch - r * RB;
      *(u16x8*)(Fout + (size_t)(tm + r) * fstride + (size_t)tn * 9 + o * 8) =
          *(const u16x8*)(Fl + (size_t)ch * 8);
    }
  } else {
    float* Cp = (float*)outv;
#pragma unroll
    for (int r = 0; r < 16; ++r) {
      int row = tm + wm + rbase + (r & 3) + 8 * (r >> 2);
      Cp[(size_t)row * N + tn + wn + col] = accv[r];
    }
  }
}

extern "C" void kernel_launch(void* const* d_in, const int* in_sizes, int n_in,
                              void* d_out, int out_size, void* d_ws, size_t ws_size,
                              hipStream_t stream) {
  (void)in_sizes; (void)n_in; (void)out_size; (void)ws_size;
  const float* x     = (const float*)d_in[0];   // 4096x1024
  const float* W1    = (const float*)d_in[1];   // 256x1024
  const float* b1    = (const float*)d_in[2];   // 256
  const float* grid1 = (const float*)d_in[3];   // 256x12 (rows identical)
  const float* coef1 = (const float*)d_in[4];   // 256x256x8
  const float* sb1   = (const float*)d_in[5];
  const float* sp1   = (const float*)d_in[6];
  const float* mask1 = (const float*)d_in[7];
  const float* grid2 = (const float*)d_in[8];
  const float* coef2 = (const float*)d_in[9];   // 256x128x8
  const float* sb2   = (const float*)d_in[10];
  const float* sp2   = (const float*)d_in[11];
  const float* mask2 = (const float*)d_in[12];
  float* outp = (float*)d_out;

  char* ws = (char*)d_ws;
  size_t off = 0;
  auto alloc = [&](size_t bytes) {
    char* p = ws + off;
    off += (bytes + 255) & ~(size_t)255;
    return (void*)p;
  };
  u16* xs_hi  = (u16*)alloc((size_t)4096 * 1024 * 2);
  u16* xs_lo  = (u16*)alloc((size_t)4096 * 1024 * 2);
  u16* w1_hi  = (u16*)alloc((size_t)256 * 1024 * 2);
  u16* w1_lo  = (u16*)alloc((size_t)256 * 1024 * 2);
  u16* wc1    = (u16*)alloc((size_t)256 * K2L * 2);
  u16* wc2    = (u16*)alloc((size_t)128 * K2L * 2);
  u16* F1     = (u16*)alloc((size_t)4096 * K2L * 2);
  u16* F2     = (u16*)alloc((size_t)4096 * K2L * 2);

  // merged prep: split x, split W1, Wc1, Wc2 (4096+256+2304+1152 = 7808 blocks)
  prep_kernel<<<7808, 256, 0, stream>>>(x, W1, coef1, sb1, sp1, mask1,
                                        coef2, sb2, sp2, mask2,
                                        xs_hi, xs_lo, w1_hi, w1_lo, wc1, wc2);

  // L1: F1 = expand(x @ W1^T + b1); bf16x3, 4 waves, BM=BN=64, grid 256
  fused_gemm<2, 2, 2, true><<<256, 256, 0, stream>>>(
      xs_hi, xs_lo, w1_hi, w1_lo, b1, grid1, F1, 4096, 256, 1024);

  // L2: F2 = expand(F1 @ Wc1^T); bf16, 4 waves, BM=BN=64, grid 256
  fused_gemm<1, 2, 2, true><<<256, 256, 0, stream>>>(
      F1, nullptr, wc1, nullptr, nullptr, grid2, F2, 4096, 256, 2304);

  // L3: out = F2 @ Wc2^T; bf16, 2 waves, BM=64 BN=32, grid 256
  fused_gemm<1, 2, 1, false><<<256, 128, 0, stream>>>(
      F2, nullptr, wc2, nullptr, nullptr, nullptr, outp, 4096, 128, 2304);
}

// Round 6
// 72.992 us; speedup vs baseline: 1.7713x; 1.0481x over previous
//
#include <hip/hip_runtime.h>
#include <math.h>

typedef unsigned short u16;
typedef u16 u16x4 __attribute__((ext_vector_type(4)));
typedef u16 u16x8 __attribute__((ext_vector_type(8)));
typedef float f32x4 __attribute__((ext_vector_type(4)));
typedef float f32x16 __attribute__((ext_vector_type(16)));
typedef __bf16 bf16x8 __attribute__((ext_vector_type(8)));

#define KC 8
#define K2L 2304  // 256*9

__device__ __forceinline__ u16 f2bf_rne(float f) {
  unsigned u = __float_as_uint(f);
  u += 0x7FFFu + ((u >> 16) & 1u);
  return (u16)(u >> 16);
}
__device__ __forceinline__ float bf2f(u16 h) {
  return __uint_as_float(((unsigned)h) << 16);
}

// async global->LDS, 16B/lane; LDS dest is the WAVE-UNIFORM base (HW adds lane*16)
__device__ __forceinline__ void gload16(const u16* g, u16* l) {
  __builtin_amdgcn_global_load_lds(
      (const __attribute__((address_space(1))) unsigned*)g,
      (__attribute__((address_space(3))) unsigned*)l, 16, 0, 0);
}

template <int N>
__device__ __forceinline__ void vmwait() {
  if constexpr (N == 0)       asm volatile("s_waitcnt vmcnt(0)" ::: "memory");
  else if constexpr (N == 8)  asm volatile("s_waitcnt vmcnt(8)" ::: "memory");
  else if constexpr (N == 12) asm volatile("s_waitcnt vmcnt(12)" ::: "memory");
  else if constexpr (N == 16) asm volatile("s_waitcnt vmcnt(16)" ::: "memory");
  else if constexpr (N == 24) asm volatile("s_waitcnt vmcnt(24)" ::: "memory");
  else static_assert(N == 0, "unsupported vmcnt literal");
}

// ---- merged prep: split x, split W1, build Wc1, Wc2 ----
__device__ __forceinline__ void split4(const float* X, u16* hi, u16* lo, int i) {
  f32x4 v = ((const f32x4*)X)[i];
  u16x4 h, l;
#pragma unroll
  for (int c = 0; c < 4; ++c) {
    u16 hb = f2bf_rne(v[c]);
    h[c] = hb;
    l[c] = f2bf_rne(v[c] - bf2f(hb));
  }
  ((u16x4*)hi)[i] = h;
  ((u16x4*)lo)[i] = l;
}
__device__ __forceinline__ void wc_one(const float* coef, const float* sb, const float* sp,
                                       const float* mask, u16* W, int N, int idx) {
  int o = idx / K2L;
  int r = idx - o * K2L;
  int i = r / 9;
  int c = r - i * 9;
  int io = i * N + o;
  float m = mask[io];
  float v = (c == 0) ? m * sb[io] : m * sp[io] * coef[(size_t)io * KC + (c - 1)];
  W[idx] = f2bf_rne(v);
}

__global__ void prep_kernel(const float* __restrict__ x, const float* __restrict__ W1,
                            const float* __restrict__ coef1, const float* __restrict__ sb1,
                            const float* __restrict__ sp1, const float* __restrict__ mask1,
                            const float* __restrict__ coef2, const float* __restrict__ sb2,
                            const float* __restrict__ sp2, const float* __restrict__ mask2,
                            u16* __restrict__ xs_hi, u16* __restrict__ xs_lo,
                            u16* __restrict__ w1_hi, u16* __restrict__ w1_lo,
                            u16* __restrict__ wc1, u16* __restrict__ wc2) {
  const int b = blockIdx.x, tid = threadIdx.x;
  if (b < 4096) {                       // split x: 1048576 quads
    split4(x, xs_hi, xs_lo, b * 256 + tid);
  } else if (b < 4096 + 256) {          // split W1: 65536 quads
    split4(W1, w1_hi, w1_lo, (b - 4096) * 256 + tid);
  } else if (b < 4096 + 256 + 2304) {   // Wc1: 589824 elems
    wc_one(coef1, sb1, sp1, mask1, wc1, 256, (b - 4352) * 256 + tid);
  } else {                              // Wc2: 294912 elems
    wc_one(coef2, sb2, sp2, mask2, wc2, 128, (b - 6656) * 256 + tid);
  }
}

// ---- spline tables: grid + precomputed reciprocal denominators ----
struct Spl {
  float g[12];
  float d1[11], d2[10], d3[9];
};
__device__ __forceinline__ void spl_init(const float* __restrict__ grid, Spl& sp) {
#pragma unroll
  for (int j = 0; j < 12; ++j) sp.g[j] = grid[j];
#pragma unroll
  for (int j = 0; j < 11; ++j) sp.d1[j] = 1.0f / (sp.g[j + 1] - sp.g[j]);
#pragma unroll
  for (int j = 0; j < 10; ++j) sp.d2[j] = 1.0f / (sp.g[j + 2] - sp.g[j]);
#pragma unroll
  for (int j = 0; j < 9; ++j) sp.d3[j] = 1.0f / (sp.g[j + 3] - sp.g[j]);
}

__device__ __forceinline__ void expand_one(float v, const Spl& sp, u16* dst) {
  float Bv[11];
#pragma unroll
  for (int j = 0; j < 11; ++j) Bv[j] = (v >= sp.g[j] && v < sp.g[j + 1]) ? 1.0f : 0.0f;
#pragma unroll
  for (int j = 0; j < 10; ++j)
    Bv[j] = (v - sp.g[j]) * sp.d1[j] * Bv[j] + (sp.g[j + 2] - v) * sp.d1[j + 1] * Bv[j + 1];
#pragma unroll
  for (int j = 0; j < 9; ++j)
    Bv[j] = (v - sp.g[j]) * sp.d2[j] * Bv[j] + (sp.g[j + 3] - v) * sp.d2[j + 1] * Bv[j + 1];
#pragma unroll
  for (int j = 0; j < 8; ++j)
    Bv[j] = (v - sp.g[j]) * sp.d3[j] * Bv[j] + (sp.g[j + 4] - v) * sp.d3[j + 1] * Bv[j + 1];
  dst[0] = f2bf_rne(v / (1.0f + __expf(-v)));  // silu
#pragma unroll
  for (int k = 0; k < 8; ++k) dst[1 + k] = f2bf_rne(Bv[k]);
}

// ---- unified MFMA GEMM, 32x32x16 bf16, BK=128, 4-buf ring, 1 barrier/step ----
// C[M,N] = A[M,K'] @ B[N,K']^T with K' possibly region-concatenated:
//   NREG==3 (split-precision bf16x3): K'=3*K, regions of K (=1024) each:
//     reg0 (Ahi,Bhi), reg1 (Ahi,Blo), reg2 (Alo,Bhi)  == hh + hl + lh
//   NREG==1: plain bf16, K'=K.
// WMxWN waves, wave-tile 32x32, BM=WM*32, BN=WN*32.
// Staging: linear LDS dest (global_load_lds) + inverse-swizzled global SOURCE
// + swizzled LDS READ; 16 slots/row XOR row&15 -> 2-way banks (free).
// Pipeline: depth-2 prefetch over 4 buffers, counted vmcnt, single s_barrier
// per step (stage at iter i writes buf[(i+2)&3]; its last readers were iter
// i-2, and all waves passed barrier(i-1) after those reads -> race-free).
template <int NREG, int WM, int WN, bool EXPAND>
__global__ __launch_bounds__(WM * WN * 64) void fused_gemm(
    const u16* __restrict__ A0, const u16* __restrict__ A1,
    const u16* __restrict__ B0, const u16* __restrict__ B1,
    const float* __restrict__ bias, const float* __restrict__ grid,
    void* __restrict__ outv, int M, int N, int K, int nsteps) {
  constexpr int THREADS = WM * WN * 64;
  constexpr int BM = WM * 32, BN = WN * 32;
  constexpr int ASZ = BM * 128;  // u16 per A tile (BK=128)
  constexpr int BSZ = BN * 128;
  constexpr int BUF_U16 = ASZ + BSZ;
  constexpr int CA = (BM * 16) / THREADS;  // 16B chunks per thread (A)
  constexpr int CB = (BN * 16) / THREADS;
  constexpr int LPT = CA + CB;             // gloads per thread per stage
  constexpr int STAGE_B = 4 * BUF_U16 * 2;
  constexpr int EXP_B = EXPAND ? BM * BN * 9 * 2 : 0;
  constexpr int SMEM = (STAGE_B > EXP_B) ? STAGE_B : EXP_B;
  __shared__ __align__(16) char smraw[SMEM];
  u16* smu = (u16*)smraw;

  const int tid = threadIdx.x;
  const int lane = tid & 63;
  const int wid = tid >> 6;

  // XCD-aware swizzle (grids here are multiples of 8)
  const int nb = N / BN;
  const int nwg = (M / BM) * nb;
  const int bid = blockIdx.x;
  const int swz = (bid & 7) * (nwg >> 3) + (bid >> 3);
  const int tm = (swz / nb) * BM;
  const int tn = (swz % nb) * BN;

  const size_t gAoff = (size_t)tm * K;
  const size_t gBoff = (size_t)tn * K;

  // chunk c: row=c>>4, slot s=c&15; slot s sources logical k-group s^(row&15)
  auto srcOff = [&](int c) -> size_t {
    int r = c >> 4, s = c & 15;
    return (size_t)r * K + (size_t)(((s ^ (r & 15)) & 15) << 3);
  };
  size_t aSrc[CA], bSrc[CB];
#pragma unroll
  for (int c = 0; c < CA; ++c) aSrc[c] = srcOff(tid + c * THREADS);
#pragma unroll
  for (int c = 0; c < CB; ++c) bSrc[c] = srcOff(tid + c * THREADS);

  const int wm = (wid / WN) * 32;
  const int wn = (wid % WN) * 32;
  const int lr = lane & 31;   // fragment row/col
  const int khf = lane >> 5;  // k-half selector

  // swizzled LDS read offsets (u16): row*128 + ((ks*2+khf)^(row&15))*8
  int offA[8], offB[8];
#pragma unroll
  for (int ks = 0; ks < 8; ++ks) {
    int rowA = wm + lr;
    int rowB = wn + lr;
    offA[ks] = rowA * 128 + ((((ks * 2 + khf) ^ (rowA & 15)) & 15) << 3);
    offB[ks] = rowB * 128 + ((((ks * 2 + khf) ^ (rowB & 15)) & 15) << 3);
  }

  auto stage = [&](int buf, int step) {
    int kk;
    const u16 *Ab, *Bb;
    if constexpr (NREG == 3) {
      int reg = step >> 3;  // K==1024 -> 8 steps per region
      kk = (step & 7) << 7;
      Ab = (reg == 2) ? A1 : A0;
      Bb = (reg == 1) ? B1 : B0;
    } else {
      kk = step << 7;
      Ab = A0;
      Bb = B0;
    }
    u16* sb = smu + buf * BUF_U16;
#pragma unroll
    for (int c = 0; c < CA; ++c)
      gload16(Ab + gAoff + aSrc[c] + kk, sb + (c * THREADS + wid * 64) * 8);
#pragma unroll
    for (int c = 0; c < CB; ++c)
      gload16(Bb + gBoff + bSrc[c] + kk, sb + ASZ + (c * THREADS + wid * 64) * 8);
  };

  f32x16 acc0 = {}, acc1 = {};
  stage(0, 0);
  stage(1, 1);
  for (int i = 0; i < nsteps; ++i) {
    if (i + 2 < nsteps) {
      stage((i + 2) & 3, i + 2);
      vmwait<2 * LPT>();  // my loads for buf[i&3] landed; 2 stages in flight
    } else if (i + 1 < nsteps) {
      vmwait<LPT>();
    } else {
      vmwait<0>();
    }
    __builtin_amdgcn_sched_barrier(0);
    __builtin_amdgcn_s_barrier();  // everyone's loads for buf[i&3] landed;
                                   // also fences reads of buf[(i+2)&3] (iter i-2)
    __builtin_amdgcn_sched_barrier(0);

    const u16* sb = smu + (i & 3) * BUF_U16;
    bf16x8 af[8], bfr[8];
#pragma unroll
    for (int ks = 0; ks < 8; ++ks) {
      af[ks] = *(const bf16x8*)(sb + offA[ks]);
      bfr[ks] = *(const bf16x8*)(sb + ASZ + offB[ks]);
    }
#pragma unroll
    for (int ks = 0; ks < 8; ++ks) {
      f32x16& ac = (ks & 1) ? acc1 : acc0;  // 2 chains for MFMA ILP
      ac = __builtin_amdgcn_mfma_f32_32x32x16_bf16(af[ks], bfr[ks], ac, 0, 0, 0);
    }
  }
  f32x16 accv = acc0 + acc1;

  // C/D layout (m74/m101): col = lane&31, row = (r&3) + 8*(r>>2) + 4*(lane>>5)
  const int col = lr;
  const int rbase = 4 * khf;
  if constexpr (EXPAND) {
    Spl sp;
    spl_init(grid, sp);
    __syncthreads();  // all waves done with stage LDS; reuse for F tile
    u16* Fl = smu;
    const float bv = bias ? bias[tn + wn + col] : 0.0f;
#pragma unroll
    for (int r = 0; r < 16; ++r) {
      int row = wm + rbase + (r & 3) + 8 * (r >> 2);
      expand_one(accv[r] + bv, sp, Fl + (size_t)row * (BN * 9) + (wn + col) * 9);
    }
    __syncthreads();
    // coalesced copy-out: BM x (BN*9) bf16 in 16B chunks
    u16* Fout = (u16*)outv;
    constexpr int RB = BN * 9 / 8;
    constexpr int CH = BM * RB;
    const size_t fstride = (size_t)N * 9;
#pragma unroll 2
    for (int ch = tid; ch < CH; ch += THREADS) {
      int r = ch / RB, o = ch - r * RB;
      *(u16x8*)(Fout + (size_t)(tm + r) * fstride + (size_t)tn * 9 + o * 8) =
          *(const u16x8*)(Fl + (size_t)ch * 8);
    }
  } else {
    float* Cp = (float*)outv;
#pragma unroll
    for (int r = 0; r < 16; ++r) {
      int row = tm + wm + rbase + (r & 3) + 8 * (r >> 2);
      Cp[(size_t)row * N + tn + wn + col] = accv[r];
    }
  }
}

extern "C" void kernel_launch(void* const* d_in, const int* in_sizes, int n_in,
                              void* d_out, int out_size, void* d_ws, size_t ws_size,
                              hipStream_t stream) {
  (void)in_sizes; (void)n_in; (void)out_size; (void)ws_size;
  const float* x     = (const float*)d_in[0];   // 4096x1024
  const float* W1    = (const float*)d_in[1];   // 256x1024
  const float* b1    = (const float*)d_in[2];   // 256
  const float* grid1 = (const float*)d_in[3];   // 256x12 (rows identical)
  const float* coef1 = (const float*)d_in[4];   // 256x256x8
  const float* sb1   = (const float*)d_in[5];
  const float* sp1   = (const float*)d_in[6];
  const float* mask1 = (const float*)d_in[7];
  const float* grid2 = (const float*)d_in[8];
  const float* coef2 = (const float*)d_in[9];   // 256x128x8
  const float* sb2   = (const float*)d_in[10];
  const float* sp2   = (const float*)d_in[11];
  const float* mask2 = (const float*)d_in[12];
  float* outp = (float*)d_out;

  char* ws = (char*)d_ws;
  size_t off = 0;
  auto alloc = [&](size_t bytes) {
    char* p = ws + off;
    off += (bytes + 255) & ~(size_t)255;
    return (void*)p;
  };
  u16* xs_hi  = (u16*)alloc((size_t)4096 * 1024 * 2);
  u16* xs_lo  = (u16*)alloc((size_t)4096 * 1024 * 2);
  u16* w1_hi  = (u16*)alloc((size_t)256 * 1024 * 2);
  u16* w1_lo  = (u16*)alloc((size_t)256 * 1024 * 2);
  u16* wc1    = (u16*)alloc((size_t)256 * K2L * 2);
  u16* wc2    = (u16*)alloc((size_t)128 * K2L * 2);
  u16* F1     = (u16*)alloc((size_t)4096 * K2L * 2);
  u16* F2     = (u16*)alloc((size_t)4096 * K2L * 2);

  // merged prep: split x, split W1, Wc1, Wc2
  prep_kernel<<<7808, 256, 0, stream>>>(x, W1, coef1, sb1, sp1, mask1,
                                        coef2, sb2, sp2, mask2,
                                        xs_hi, xs_lo, w1_hi, w1_lo, wc1, wc2);

  // L1: F1 = expand(x @ W1^T + b1); bf16x3 as K'=3072 region-GEMM; 24 steps
  fused_gemm<3, 2, 2, true><<<256, 256, 0, stream>>>(
      xs_hi, xs_lo, w1_hi, w1_lo, b1, grid1, F1, 4096, 256, 1024, 24);

  // L2: F2 = expand(F1 @ Wc1^T); plain bf16, K=2304; 18 steps
  fused_gemm<1, 2, 2, true><<<256, 256, 0, stream>>>(
      F1, nullptr, wc1, nullptr, nullptr, grid2, F2, 4096, 256, 2304, 18);

  // L3: out = F2 @ Wc2^T; plain bf16, BM=64 BN=32, grid 256; 18 steps
  fused_gemm<1, 2, 1, false><<<256, 128, 0, stream>>>(
      F2, nullptr, wc2, nullptr, nullptr, nullptr, outp, 4096, 128, 2304, 18);
}